// Round 15
// baseline (645.587 us; speedup 1.0000x reference)
//
#include <hip/hip_runtime.h>
#include <math.h>

#define NCLS 9

typedef __attribute__((ext_vector_type(8))) short short8;
typedef __attribute__((ext_vector_type(4))) float f32x4;

__device__ __forceinline__ unsigned short f2bf(float f) {
    unsigned int u = __float_as_uint(f);
    return (unsigned short)((u + 0x7fffu + ((u >> 16) & 1u)) >> 16);  // RNE
}

__device__ __forceinline__ short8 as_s8(uint4 v) {
    union { uint4 u; short8 s; } x; x.u = v; return x.s;
}

__device__ __forceinline__ float fast_tanh(float x) {
    // tanh(x) = 1 - 2/(2^(x*2*log2e) + 1); saturates correctly at +/-1
    float s = x * 2.885390081777927f;
    float e, r;
    asm("v_exp_f32 %0, %1" : "=v"(e) : "v"(s));
    asm("v_rcp_f32 %0, %1" : "=v"(r) : "v"(e + 1.0f));
    return fmaf(-2.0f, r, 1.0f);
}

// Fused 2-layer persistent MFMA RNN (R11 structure, bench-proven 595us).
// M=2 rows/block, 256 blocks (1/CU), 512 threads (8 waves, 2/SIMD).
// Wave w owns 32 output cols (2 B-tiles, 64 pinned VGPR -- the only
// allocator-stable count; C=64 died on the register wall in R3/4/7/9/13).
// Paired-column map col = w*32 + 2c + t2 -> one v_cvt_pk_bf16_f32 + one b32
// write per row.
//
// ROW-DUPLICATION: lane (g,l16) reads A row (l16&1); 8 lanes share each
// address (same-address broadcast = free); C rows 2..15 are consistent
// duplicates; only rows 0..1 kept.
//
// h LDS: 64 cells x 16B per buffer; cell (kk,g2,m) = idx kk*8+g2*2+m holds
// k = kk*32+g2*8+0..7 of row m.
//  - A-read (per kk): 8 distinct contiguous cells, 1 word/bank, bcast x8.
//  - h-write (g==0): b32, 16 distinct banks, conflict-free.
// Step cost ~1050 cyc, ~860 of it DS-datapath (64 ds_read_b128 + writes):
// the structural floor for the 8-wave full-K broadcast scheme.
//
// R15 delta vs R11: padded xall/seq2 (+1 entry) removes the per-step
// clamp-select on the sv prefetch. MLP stays a separate kernel (fusing it
// in-block measured +46us in R14 -- reverted).
__global__ __launch_bounds__(512, 2) void rnn_fused_kernel(
    const float* __restrict__ x,     // [B, 1024]
    const float* __restrict__ W1, const float* __restrict__ U1, const float* __restrict__ b1,
    const float* __restrict__ W2, const float* __restrict__ U2, const float* __restrict__ b2,
    float* __restrict__ h2out)       // [B, 256]
{
    const int tid  = threadIdx.x;
    const int w    = tid >> 6;
    const int lane = tid & 63;
    const int g    = lane >> 4;
    const int l16  = lane & 15;
    const int b0   = blockIdx.x << 1;   // 2 rows per block

    __shared__ uint4  hbuf[2][64];    // 2 x 1KB h double-buffer (cell layout)
    __shared__ float2 xall[1025];     // 8KB+pad: x staged [t]{row0,row1}
    __shared__ float2 seq2[257];      // 2KB+pad: layer-2 input [col]{row0,row1}

    // ---- stage all of x (once) + zero both h buffers ----
    {
        const float4* x4 = (const float4*)x;
        const int row = tid >> 8, tq = tid & 255;      // 512 threads = 2x256
        const float4 v = x4[(b0 + row) * 256 + tq];
        ((float*)&xall[tq * 4 + 0])[row] = v.x;
        ((float*)&xall[tq * 4 + 1])[row] = v.y;
        ((float*)&xall[tq * 4 + 2])[row] = v.z;
        ((float*)&xall[tq * 4 + 3])[row] = v.w;
        ((unsigned int*)hbuf)[tid] = 0u;               // 512 u32 = both buffers
        if (tid == 0) xall[1024] = make_float2(0.f, 0.f);   // prefetch pad
    }

    // ---- hoisted LDS byte offsets ----
    int rd_off[8];
    #pragma unroll
    for (int kk = 0; kk < 8; ++kk)
        rd_off[kk] = (kk * 8 + g * 2 + (l16 & 1)) << 4;
    const int g2w = (l16 >> 2) & 3, s4 = l16 & 3;
    int wr_off[2];
    #pragma unroll
    for (int r = 0; r < 2; ++r)
        wr_off[r] = ((w * 8 + g2w * 2 + r) << 4) + 4 * s4;
    const int col0 = w * 32 + 2 * l16;
    char* const hbase = (char*)hbuf;

#pragma unroll 1
    for (int p = 0; p < 2; ++p) {
        const float* W    = p ? W2 : W1;
        const float* U    = p ? U2 : U1;
        const float* bias = p ? b2 : b1;
        const int    T    = p ? 256 : 1024;

        // ---- B-fragments (bf16, pinned registers); col = w*32 + 2c + t2 ----
        uint4 bfrag[2][8];
        #pragma unroll
        for (int t2 = 0; t2 < 2; ++t2) {
            #pragma unroll
            for (int kk = 0; kk < 8; ++kk) {
                unsigned int d[4];
                #pragma unroll
                for (int pr = 0; pr < 4; ++pr) {
                    const int k0 = kk * 32 + g * 8 + 2 * pr;
                    d[pr] = (unsigned)f2bf(U[k0 * 256 + col0 + t2])
                          | ((unsigned)f2bf(U[(k0 + 1) * 256 + col0 + t2]) << 16);
                }
                bfrag[t2][kk] = make_uint4(d[0], d[1], d[2], d[3]);
            }
        }
        #pragma unroll
        for (int t2 = 0; t2 < 2; ++t2)
            #pragma unroll
            for (int kk = 0; kk < 8; ++kk)
                asm volatile("" : "+v"(bfrag[t2][kk].x), "+v"(bfrag[t2][kk].y),
                                  "+v"(bfrag[t2][kk].z), "+v"(bfrag[t2][kk].w));

        const float2 wv2 = *(const float2*)&W[col0];
        const float2 bv2 = *(const float2*)&bias[col0];

        if (p == 1) {
            // re-zero h buffer 0 for layer 2 (first 1KB = 256 u32)
            if (tid < 256) ((unsigned int*)hbuf)[tid] = 0u;
            if (tid == 0) seq2[256] = make_float2(0.f, 0.f);   // prefetch pad
        }
        __syncthreads();

        const float2* const svp = p ? seq2 : xall;
        float2 svc = svp[0];

        for (int t = 0; t < T; ++t) {
            char* const hcur = hbase + ((t & 1) << 10);
            char* const hnxt = hbase + (((t & 1) ^ 1) << 10);

            // A-fragments: 8 x ds_read_b128, 8 distinct cells, x8 broadcast
            uint4 a[8];
            #pragma unroll
            for (int kk = 0; kk < 8; ++kk)
                a[kk] = *(const uint4*)(hcur + rd_off[kk]);

            // acc init = input projection + bias; rows 2..15 mirror 0..1
            f32x4 aA0, aA1;
            f32x4 aB0 = {0.f, 0.f, 0.f, 0.f}, aB1 = {0.f, 0.f, 0.f, 0.f};
            aA0[0] = fmaf(svc.x, wv2.x, bv2.x);
            aA0[1] = fmaf(svc.y, wv2.x, bv2.x);
            aA0[2] = aA0[0]; aA0[3] = aA0[1];
            aA1[0] = fmaf(svc.x, wv2.y, bv2.y);
            aA1[1] = fmaf(svc.y, wv2.y, bv2.y);
            aA1[2] = aA1[0]; aA1[3] = aA1[1];

            // 4 independent 4-deep MFMA chains (2 tiles x even/odd kk)
            #pragma unroll
            for (int kp = 0; kp < 4; ++kp) {
                aA0 = __builtin_amdgcn_mfma_f32_16x16x32_bf16(
                    as_s8(a[2 * kp]), as_s8(bfrag[0][2 * kp]), aA0, 0, 0, 0);
                aA1 = __builtin_amdgcn_mfma_f32_16x16x32_bf16(
                    as_s8(a[2 * kp]), as_s8(bfrag[1][2 * kp]), aA1, 0, 0, 0);
                aB0 = __builtin_amdgcn_mfma_f32_16x16x32_bf16(
                    as_s8(a[2 * kp + 1]), as_s8(bfrag[0][2 * kp + 1]), aB0, 0, 0, 0);
                aB1 = __builtin_amdgcn_mfma_f32_16x16x32_bf16(
                    as_s8(a[2 * kp + 1]), as_s8(bfrag[1][2 * kp + 1]), aB1, 0, 0, 0);
            }

            // prefetch sv for t+1 (padded arrays: no select)
            svc = svp[t + 1];

            // epilogue: only rows 0,1 are real
            const float h00 = fast_tanh(aA0[0] + aB0[0]);   // col0,   row0
            const float h01 = fast_tanh(aA0[1] + aB0[1]);   // col0,   row1
            const float h10 = fast_tanh(aA1[0] + aB1[0]);   // col0+1, row0
            const float h11 = fast_tanh(aA1[1] + aB1[1]);   // col0+1, row1
            unsigned pk0, pk1;
            asm("v_cvt_pk_bf16_f32 %0, %1, %2" : "=v"(pk0) : "v"(h00), "v"(h10));
            asm("v_cvt_pk_bf16_f32 %0, %1, %2" : "=v"(pk1) : "v"(h01), "v"(h11));

            if (g == 0) {
                *(unsigned int*)(hnxt + wr_off[0]) = pk0;   // row 0
                *(unsigned int*)(hnxt + wr_off[1]) = pk1;   // row 1
                if (t == T - 1) {
                    if (p == 0) {
                        seq2[col0]     = make_float2(h00, h01);
                        seq2[col0 + 1] = make_float2(h10, h11);
                    } else {
                        *(float2*)&h2out[(b0 + 0) * 256 + col0] = make_float2(h00, h10);
                        *(float2*)&h2out[(b0 + 1) * 256 + col0] = make_float2(h01, h11);
                    }
                }
            }
            __syncthreads();
        }
    }
}

// Tiny MLP head: one block per batch row, 128 threads (separate launch --
// measured faster than in-block fusion, R14).
__global__ __launch_bounds__(128) void mlp_kernel(
    const float* __restrict__ h2,
    const float* __restrict__ Wd1, const float* __restrict__ bd1,
    const float* __restrict__ Wd2, const float* __restrict__ bd2,
    const float* __restrict__ Wd3, const float* __restrict__ bd3,
    const float* __restrict__ Wd4, const float* __restrict__ bd4,
    float* __restrict__ out)
{
    const int b   = blockIdx.x;
    const int tid = threadIdx.x;

    __shared__ float hin[256];
    __shared__ float z1[128];
    __shared__ float z2[64];
    __shared__ float z3[32];

    hin[tid]       = h2[b * 256 + tid];
    hin[tid + 128] = h2[b * 256 + tid + 128];
    __syncthreads();

    {
        float a = bd1[tid];
#pragma unroll 8
        for (int i = 0; i < 256; ++i) a += hin[i] * Wd1[i * 128 + tid];
        z1[tid] = fmaxf(a, 0.0f);
    }
    __syncthreads();
    if (tid < 64) {
        float a = bd2[tid];
#pragma unroll 8
        for (int i = 0; i < 128; ++i) a += z1[i] * Wd2[i * 64 + tid];
        z2[tid] = fmaxf(a, 0.0f);
    }
    __syncthreads();
    if (tid < 32) {
        float a = bd3[tid];
#pragma unroll 8
        for (int i = 0; i < 64; ++i) a += z2[i] * Wd3[i * 32 + tid];
        z3[tid] = fmaxf(a, 0.0f);
    }
    __syncthreads();
    if (tid < NCLS) {
        float a = bd4[tid];
#pragma unroll
        for (int i = 0; i < 32; ++i) a += z3[i] * Wd4[i * NCLS + tid];
        out[b * NCLS + tid] = a;
    }
}

extern "C" void kernel_launch(void* const* d_in, const int* in_sizes, int n_in,
                              void* d_out, int out_size, void* d_ws, size_t ws_size,
                              hipStream_t stream) {
    const float* x   = (const float*)d_in[0];
    const float* W1  = (const float*)d_in[1];
    const float* U1  = (const float*)d_in[2];
    const float* b1  = (const float*)d_in[3];
    const float* W2  = (const float*)d_in[4];
    const float* U2  = (const float*)d_in[5];
    const float* b2  = (const float*)d_in[6];
    const float* Wd1 = (const float*)d_in[7];
    const float* bd1 = (const float*)d_in[8];
    const float* Wd2 = (const float*)d_in[9];
    const float* bd2 = (const float*)d_in[10];
    const float* Wd3 = (const float*)d_in[11];
    const float* bd3 = (const float*)d_in[12];
    const float* Wd4 = (const float*)d_in[13];
    const float* bd4 = (const float*)d_in[14];

    float* out = (float*)d_out;
    float* h2  = (float*)d_ws;        // 512*256 fp32

    rnn_fused_kernel<<<256, 512, 0, stream>>>(x, W1, U1, b1, W2, U2, b2, h2);
    mlp_kernel<<<512, 128, 0, stream>>>(h2, Wd1, bd1, Wd2, bd2, Wd3, bd3, Wd4, bd4, out);
}

// Round 16
// 596.548 us; speedup vs baseline: 1.0822x; 1.0822x over previous
//
#include <hip/hip_runtime.h>
#include <math.h>

#define NCLS 9

typedef __attribute__((ext_vector_type(8))) short short8;
typedef __attribute__((ext_vector_type(4))) float f32x4;

__device__ __forceinline__ unsigned short f2bf(float f) {
    unsigned int u = __float_as_uint(f);
    return (unsigned short)((u + 0x7fffu + ((u >> 16) & 1u)) >> 16);  // RNE
}

__device__ __forceinline__ short8 as_s8(uint4 v) {
    union { uint4 u; short8 s; } x; x.u = v; return x.s;
}

__device__ __forceinline__ float fast_tanh(float x) {
    // tanh(x) = 1 - 2/(2^(x*2*log2e) + 1); saturates correctly at +/-1
    float s = x * 2.885390081777927f;
    float e, r;
    asm("v_exp_f32 %0, %1" : "=v"(e) : "v"(s));
    asm("v_rcp_f32 %0, %1" : "=v"(r) : "v"(e + 1.0f));
    return fmaf(-2.0f, r, 1.0f);
}

// Fused 2-layer persistent MFMA RNN, M=2 rows/block, 256 blocks (full chip).
// 512 threads (8 waves, 2/SIMD). Wave w owns 32 output cols (2 B-tiles,
// 64 pinned VGPR), paired-column map col = w*32 + 2c + t2.
//
// ROW-DUPLICATION TRICK: the MFMA A-operand wants rows lane&15; with only 2
// real rows, lane (g,l16) reads row (l16&1) -- 8 lanes share each address
// (same-address broadcast = free) -- so A rows 2..15 are duplicates of 0..1,
// C rows 2..15 are consistent duplicates, and only C rows 0..1 (g==0,
// r∈{0,1}) are kept. DS A-traffic per instr: 128B distinct vs 1KB at M=16.
//
// h LDS: 64 cells x 16B per buffer; cell (kk,g2,m) = idx kk*8+g2*2+m holds
// k = kk*32+g2*8+0..7 of row m.
//  - A-read (per kk): 8 distinct contiguous cells, 1 word/bank, broadcast x8.
//  - h-write (g==0 lanes): bank = g2w*8 + 4r + s4 -> 16 distinct banks,
//    conflict-free, 2 x b32 per lane.
// Per-CU DS/step ~450 cyc vs R8's ~1050; epilogue halves (r<2 only).
//
// Bench-proven configuration (R11: 595us total). Structural alternatives all
// measured worse: C=64/wave (register wall, R3/4/7/9/13), K-split (R12),
// 2 blocks/CU (R13), 2 batch groups (R5), MLP fusion (R14), hoisted-pointer
// sv prefetch (R15).
__global__ __launch_bounds__(512, 2) void rnn_fused_kernel(
    const float* __restrict__ x,     // [B, 1024]
    const float* __restrict__ W1, const float* __restrict__ U1, const float* __restrict__ b1,
    const float* __restrict__ W2, const float* __restrict__ U2, const float* __restrict__ b2,
    float* __restrict__ h2out)       // [B, 256]
{
    const int tid  = threadIdx.x;
    const int w    = tid >> 6;
    const int lane = tid & 63;
    const int g    = lane >> 4;
    const int l16  = lane & 15;
    const int b0   = blockIdx.x << 1;   // 2 rows per block

    __shared__ uint4  hbuf[2][64];    // 2 x 1KB, cell layout above
    __shared__ float2 xall[1024];     // 8KB: x staged [t]{row0,row1}
    __shared__ float2 seq2[256];      // 2KB: layer-2 input [col]{row0,row1}

    // ---- stage all of x (once) + zero both h buffers ----
    {
        const float4* x4 = (const float4*)x;
        const int row = tid >> 8, tq = tid & 255;      // 512 threads = 2x256
        const float4 v = x4[(b0 + row) * 256 + tq];
        ((float*)&xall[tq * 4 + 0])[row] = v.x;
        ((float*)&xall[tq * 4 + 1])[row] = v.y;
        ((float*)&xall[tq * 4 + 2])[row] = v.z;
        ((float*)&xall[tq * 4 + 3])[row] = v.w;
        ((unsigned int*)hbuf)[tid] = 0u;               // 512 u32 = both buffers
    }

    // ---- hoisted LDS byte offsets ----
    int rd_off[8];
    #pragma unroll
    for (int kk = 0; kk < 8; ++kk)
        rd_off[kk] = (kk * 8 + g * 2 + (l16 & 1)) << 4;
    const int g2w = (l16 >> 2) & 3, s4 = l16 & 3;
    int wr_off[2];
    #pragma unroll
    for (int r = 0; r < 2; ++r)
        wr_off[r] = ((w * 8 + g2w * 2 + r) << 4) + 4 * s4;
    const int col0 = w * 32 + 2 * l16;
    char* const hbase = (char*)hbuf;

#pragma unroll 1
    for (int p = 0; p < 2; ++p) {
        const float* W    = p ? W2 : W1;
        const float* U    = p ? U2 : U1;
        const float* bias = p ? b2 : b1;
        const int    T    = p ? 256 : 1024;

        // ---- B-fragments (bf16, pinned registers); col = w*32 + 2c + t2 ----
        uint4 bfrag[2][8];
        #pragma unroll
        for (int t2 = 0; t2 < 2; ++t2) {
            #pragma unroll
            for (int kk = 0; kk < 8; ++kk) {
                unsigned int d[4];
                #pragma unroll
                for (int pr = 0; pr < 4; ++pr) {
                    const int k0 = kk * 32 + g * 8 + 2 * pr;
                    d[pr] = (unsigned)f2bf(U[k0 * 256 + col0 + t2])
                          | ((unsigned)f2bf(U[(k0 + 1) * 256 + col0 + t2]) << 16);
                }
                bfrag[t2][kk] = make_uint4(d[0], d[1], d[2], d[3]);
            }
        }
        #pragma unroll
        for (int t2 = 0; t2 < 2; ++t2)
            #pragma unroll
            for (int kk = 0; kk < 8; ++kk)
                asm volatile("" : "+v"(bfrag[t2][kk].x), "+v"(bfrag[t2][kk].y),
                                  "+v"(bfrag[t2][kk].z), "+v"(bfrag[t2][kk].w));

        const float2 wv2 = *(const float2*)&W[col0];
        const float2 bv2 = *(const float2*)&bias[col0];

        if (p == 1) {
            // re-zero h buffer 0 for layer 2 (first 1KB = 256 u32)
            if (tid < 256) ((unsigned int*)hbuf)[tid] = 0u;
        }
        __syncthreads();

        // sv prefetch for t=0 (xall/seq2 static during loop; uniform address)
        float2 svc = p ? seq2[0] : xall[0];

        for (int t = 0; t < T; ++t) {
            char* const hcur = hbase + ((t & 1) << 10);
            char* const hnxt = hbase + (((t & 1) ^ 1) << 10);

            // A-fragments: 8 x ds_read_b128, 8 distinct cells, x8 broadcast
            uint4 a[8];
            #pragma unroll
            for (int kk = 0; kk < 8; ++kk)
                a[kk] = *(const uint4*)(hcur + rd_off[kk]);

            // acc init = input projection + bias; rows 2..15 mirror 0..1 so
            // the duplicate C rows stay exactly consistent.
            f32x4 aA0, aA1;
            f32x4 aB0 = {0.f, 0.f, 0.f, 0.f}, aB1 = {0.f, 0.f, 0.f, 0.f};
            aA0[0] = fmaf(svc.x, wv2.x, bv2.x);
            aA0[1] = fmaf(svc.y, wv2.x, bv2.x);
            aA0[2] = aA0[0]; aA0[3] = aA0[1];
            aA1[0] = fmaf(svc.x, wv2.y, bv2.y);
            aA1[1] = fmaf(svc.y, wv2.y, bv2.y);
            aA1[2] = aA1[0]; aA1[3] = aA1[1];

            // 4 independent 4-deep MFMA chains (2 tiles x even/odd kk)
            #pragma unroll
            for (int kp = 0; kp < 4; ++kp) {
                aA0 = __builtin_amdgcn_mfma_f32_16x16x32_bf16(
                    as_s8(a[2 * kp]), as_s8(bfrag[0][2 * kp]), aA0, 0, 0, 0);
                aA1 = __builtin_amdgcn_mfma_f32_16x16x32_bf16(
                    as_s8(a[2 * kp]), as_s8(bfrag[1][2 * kp]), aA1, 0, 0, 0);
                aB0 = __builtin_amdgcn_mfma_f32_16x16x32_bf16(
                    as_s8(a[2 * kp + 1]), as_s8(bfrag[0][2 * kp + 1]), aB0, 0, 0, 0);
                aB1 = __builtin_amdgcn_mfma_f32_16x16x32_bf16(
                    as_s8(a[2 * kp + 1]), as_s8(bfrag[1][2 * kp + 1]), aB1, 0, 0, 0);
            }

            // prefetch sv for t+1 (uniform-address, static LDS)
            {
                const int tn = (t + 1 < T) ? t + 1 : 0;
                svc = p ? seq2[tn] : xall[tn];
            }

            // epilogue: only rows 0,1 are real
            const float h00 = fast_tanh(aA0[0] + aB0[0]);   // col0,   row0
            const float h01 = fast_tanh(aA0[1] + aB0[1]);   // col0,   row1
            const float h10 = fast_tanh(aA1[0] + aB1[0]);   // col0+1, row0
            const float h11 = fast_tanh(aA1[1] + aB1[1]);   // col0+1, row1
            unsigned pk0, pk1;
            asm("v_cvt_pk_bf16_f32 %0, %1, %2" : "=v"(pk0) : "v"(h00), "v"(h10));
            asm("v_cvt_pk_bf16_f32 %0, %1, %2" : "=v"(pk1) : "v"(h01), "v"(h11));

            if (g == 0) {
                *(unsigned int*)(hnxt + wr_off[0]) = pk0;   // row 0
                *(unsigned int*)(hnxt + wr_off[1]) = pk1;   // row 1
                if (t == T - 1) {
                    if (p == 0) {
                        seq2[col0]     = make_float2(h00, h01);
                        seq2[col0 + 1] = make_float2(h10, h11);
                    } else {
                        *(float2*)&h2out[(b0 + 0) * 256 + col0] = make_float2(h00, h10);
                        *(float2*)&h2out[(b0 + 1) * 256 + col0] = make_float2(h01, h11);
                    }
                }
            }
            __syncthreads();
        }
    }
}

// Tiny MLP head: one block per batch row, 128 threads.
__global__ __launch_bounds__(128) void mlp_kernel(
    const float* __restrict__ h2,
    const float* __restrict__ Wd1, const float* __restrict__ bd1,
    const float* __restrict__ Wd2, const float* __restrict__ bd2,
    const float* __restrict__ Wd3, const float* __restrict__ bd3,
    const float* __restrict__ Wd4, const float* __restrict__ bd4,
    float* __restrict__ out)
{
    const int b   = blockIdx.x;
    const int tid = threadIdx.x;

    __shared__ float hin[256];
    __shared__ float z1[128];
    __shared__ float z2[64];
    __shared__ float z3[32];

    hin[tid]       = h2[b * 256 + tid];
    hin[tid + 128] = h2[b * 256 + tid + 128];
    __syncthreads();

    {
        float a = bd1[tid];
#pragma unroll 8
        for (int i = 0; i < 256; ++i) a += hin[i] * Wd1[i * 128 + tid];
        z1[tid] = fmaxf(a, 0.0f);
    }
    __syncthreads();
    if (tid < 64) {
        float a = bd2[tid];
#pragma unroll 8
        for (int i = 0; i < 128; ++i) a += z1[i] * Wd2[i * 64 + tid];
        z2[tid] = fmaxf(a, 0.0f);
    }
    __syncthreads();
    if (tid < 32) {
        float a = bd3[tid];
#pragma unroll 8
        for (int i = 0; i < 64; ++i) a += z2[i] * Wd3[i * 32 + tid];
        z3[tid] = fmaxf(a, 0.0f);
    }
    __syncthreads();
    if (tid < NCLS) {
        float a = bd4[tid];
#pragma unroll
        for (int i = 0; i < 32; ++i) a += z3[i] * Wd4[i * NCLS + tid];
        out[b * NCLS + tid] = a;
    }
}

extern "C" void kernel_launch(void* const* d_in, const int* in_sizes, int n_in,
                              void* d_out, int out_size, void* d_ws, size_t ws_size,
                              hipStream_t stream) {
    const float* x   = (const float*)d_in[0];
    const float* W1  = (const float*)d_in[1];
    const float* U1  = (const float*)d_in[2];
    const float* b1  = (const float*)d_in[3];
    const float* W2  = (const float*)d_in[4];
    const float* U2  = (const float*)d_in[5];
    const float* b2  = (const float*)d_in[6];
    const float* Wd1 = (const float*)d_in[7];
    const float* bd1 = (const float*)d_in[8];
    const float* Wd2 = (const float*)d_in[9];
    const float* bd2 = (const float*)d_in[10];
    const float* Wd3 = (const float*)d_in[11];
    const float* bd3 = (const float*)d_in[12];
    const float* Wd4 = (const float*)d_in[13];
    const float* bd4 = (const float*)d_in[14];

    float* out = (float*)d_out;
    float* h2  = (float*)d_ws;        // 512*256 fp32

    rnn_fused_kernel<<<256, 512, 0, stream>>>(x, W1, U1, b1, W2, U2, b2, h2);
    mlp_kernel<<<512, 128, 0, stream>>>(h2, Wd1, bd1, Wd2, bd2, Wd3, bd3, Wd4, bd4, out);
}